// Round 7
// baseline (188.778 us; speedup 1.0000x reference)
//
#include <hip/hip_runtime.h>
#include <hip/hip_bf16.h>

#define BB 8
#define NN 2048
#define CC 320
#define CQ 64
#define LOG2E 1.4426950408889634f

typedef __attribute__((ext_vector_type(8)))  short bf16x8;
typedef __attribute__((ext_vector_type(4)))  float f32x4;
typedef __attribute__((ext_vector_type(16))) float f32x16;
typedef __attribute__((ext_vector_type(4)))  unsigned short us4;
typedef __attribute__((ext_vector_type(8)))  unsigned short us8;
typedef __attribute__((ext_vector_type(4)))  unsigned int u32x4;
typedef unsigned short u16;

static __device__ __forceinline__ u16 f2b(float f) {
  unsigned u = __builtin_bit_cast(unsigned, f);
  unsigned r = (u + 0x7FFFu + ((u >> 16) & 1u)) >> 16;
  return (u16)r;
}
static __device__ __forceinline__ float b2f(u16 s) {
  unsigned u = ((unsigned)s) << 16;
  return __builtin_bit_cast(float, u);
}

static __device__ __forceinline__ f32x16 zero16() {
  f32x16 v = {0,0,0,0, 0,0,0,0, 0,0,0,0, 0,0,0,0};
  return v;
}
static __device__ __forceinline__ f32x4 zero4() {
  f32x4 v = {0,0,0,0};
  return v;
}

// ---------------------------------------------------------------------------
// K0a: x fp32 -> xb bf16. grid 5120 x 256
// ---------------------------------------------------------------------------
__global__ __launch_bounds__(256) void cvt_x(const float* __restrict__ x,
                                             u16* __restrict__ xb) {
  const size_t i = (size_t)blockIdx.x * 256 + threadIdx.x;
  float4 v = *(const float4*)(x + i * 4);
  us4 o;
  o.x = f2b(v.x); o.y = f2b(v.y); o.z = f2b(v.z); o.w = f2b(v.w);
  *(us4*)(xb + i * 4) = o;
}

// ---------------------------------------------------------------------------
// K0b: Wq/Wk/Wv fp32 -> concat Wb[448][320] bf16. grid 140 x 256
// ---------------------------------------------------------------------------
__global__ __launch_bounds__(256) void cvt_w(const float* __restrict__ Wq,
                                             const float* __restrict__ Wk,
                                             const float* __restrict__ Wv,
                                             u16* __restrict__ Wb) {
  const int i = blockIdx.x * 256 + threadIdx.x;
  const int idx4 = i * 4;
  const int row = idx4 / CC;
  const int col = idx4 - row * CC;
  const float* src = (row < 64) ? (Wq + (size_t)row * CC)
                   : (row < 128) ? (Wk + (size_t)(row - 64) * CC)
                                 : (Wv + (size_t)(row - 128) * CC);
  float4 v = *(const float4*)(src + col);
  us4 o;
  o.x = f2b(v.x); o.y = f2b(v.y); o.z = f2b(v.z); o.w = f2b(v.w);
  *(us4*)(Wb + (size_t)row * CC + col) = o;
}

// ---------------------------------------------------------------------------
// K1: QKV GEMM. grid (7, 128). x=0: Q cols (scaled by log2e), x=1: K cols,
// x>=2: V cols written transposed into Vt[b][c][n].
// ---------------------------------------------------------------------------
__global__ __launch_bounds__(256) void gemm_qkv(
    const u16* __restrict__ xb, const u16* __restrict__ Wb,
    const float* __restrict__ bq, const float* __restrict__ bk,
    const float* __restrict__ bv,
    u16* __restrict__ Qb, u16* __restrict__ Kb, u16* __restrict__ Vt) {
  const int tid = threadIdx.x;
  const int lane = tid & 63, wid = tid >> 6;
  const int r = lane & 31, h = lane >> 5;
  const int m0 = blockIdx.y * 128 + wid * 32;
  const int col0 = blockIdx.x * 64;

  f32x16 acc0 = zero16(), acc1 = zero16();
  const u16* xrow = xb + (size_t)(m0 + r) * CC + h * 8;
  const u16* w0 = Wb + (size_t)(col0 + r) * CC + h * 8;
  const u16* w1 = w0 + 32 * CC;

  bf16x8 a   = *(const bf16x8*)(xrow);
  bf16x8 b0v = *(const bf16x8*)(w0);
  bf16x8 b1v = *(const bf16x8*)(w1);
#pragma unroll 1
  for (int ks = 0; ks < 20; ++ks) {
    bf16x8 na, nb0, nb1;
    if (ks < 19) {
      na  = *(const bf16x8*)(xrow + (ks + 1) * 16);
      nb0 = *(const bf16x8*)(w0 + (ks + 1) * 16);
      nb1 = *(const bf16x8*)(w1 + (ks + 1) * 16);
    }
    acc0 = __builtin_amdgcn_mfma_f32_32x32x16_bf16(a, b0v, acc0, 0, 0, 0);
    acc1 = __builtin_amdgcn_mfma_f32_32x32x16_bf16(a, b1v, acc1, 0, 0, 0);
    a = na; b0v = nb0; b1v = nb1;
  }

  const int bb = m0 >> 11;        // batch
  const int mloc = m0 & 2047;     // n within batch

#pragma unroll
  for (int nt = 0; nt < 2; ++nt) {
    const int col = col0 + nt * 32 + r;
    const f32x16 A = nt ? acc1 : acc0;
    if (col0 >= 128) {
      // V block: write transposed Vt[(bb*CC + c)][n], packed 4-n us4 stores
      const int c = col - 128;
      const float bias = bv[c];
      u16* vb = Vt + (((size_t)(bb * CC + c)) << 11) + mloc + 4 * h;
#pragma unroll
      for (int g = 0; g < 4; ++g) {
        us4 o;
#pragma unroll
        for (int e = 0; e < 4; ++e) o[e] = f2b(A[g * 4 + e] + bias);
        *(us4*)(vb + g * 8) = o;
      }
    } else if (col0 >= 64) {
      const float bias = bk[col - 64];
#pragma unroll
      for (int reg = 0; reg < 16; ++reg) {
        const int row = m0 + (reg & 3) + 8 * (reg >> 2) + 4 * h;
        Kb[(size_t)row * CQ + (col - 64)] = f2b(A[reg] + bias);
      }
    } else {
      // Q block: fold log2(e) so softmax exp becomes a single v_exp_f32
      const float bias = bq[col];
#pragma unroll
      for (int reg = 0; reg < 16; ++reg) {
        const int row = m0 + (reg & 3) + 8 * (reg >> 2) + 4 * h;
        Qb[(size_t)row * CQ + col] = f2b((A[reg] + bias) * LOG2E);
      }
    }
  }
}

// ---------------------------------------------------------------------------
// K3: row sums + fold 1/S into V.
// S[k] = sum_m 2^(Q'[k]·K[m]); then Vt[b][c][k] *= 1/S[k] for all c.
// Block = 64 k-rows of one batch; 4 waves cover m in 512-chunks. grid 256.
// ---------------------------------------------------------------------------
__global__ __launch_bounds__(256) void row_stats(
    const u16* __restrict__ Qb, const u16* __restrict__ Kb,
    u16* __restrict__ Vt) {
  __shared__ float Sp[4][64];
  __shared__ float sInv[64];
  const int tid = threadIdx.x;
  const int lane = tid & 63, wid = tid >> 6;
  const int rl = lane & 15, hq = lane >> 4;
  const int bid = blockIdx.x;
  const int batch = bid & 7;
  const int r0g = batch * NN + (bid >> 3) * 64;

  bf16x8 af[4][2];
#pragma unroll
  for (int mt = 0; mt < 4; ++mt)
#pragma unroll
    for (int qs = 0; qs < 2; ++qs)
      af[mt][qs] = *(const bf16x8*)(Qb + (size_t)(r0g + mt * 16 + rl) * CQ + qs * 32 + hq * 8);

  float S[4][4];
#pragma unroll
  for (int mt = 0; mt < 4; ++mt)
#pragma unroll
    for (int rr = 0; rr < 4; ++rr) S[mt][rr] = 0.f;

  const int mstart = batch * NN + wid * 512;
  const u16* kr = Kb + (size_t)(mstart + rl) * CQ + hq * 8;
  bf16x8 c0 = *(const bf16x8*)(kr);
  bf16x8 c1 = *(const bf16x8*)(kr + 32);
#pragma unroll 1
  for (int ms = 0; ms < 32; ++ms) {
    bf16x8 n0, n1;
    if (ms < 31) {
      n0 = *(const bf16x8*)(kr + 16 * CQ);
      n1 = *(const bf16x8*)(kr + 16 * CQ + 32);
    }
#pragma unroll
    for (int mt = 0; mt < 4; ++mt) {
      f32x4 e = zero4();
      e = __builtin_amdgcn_mfma_f32_16x16x32_bf16(af[mt][0], c0, e, 0, 0, 0);
      e = __builtin_amdgcn_mfma_f32_16x16x32_bf16(af[mt][1], c1, e, 0, 0, 0);
#pragma unroll
      for (int rr = 0; rr < 4; ++rr) S[mt][rr] += __builtin_amdgcn_exp2f(e[rr]);
    }
    c0 = n0; c1 = n1; kr += 16 * CQ;
  }

#pragma unroll
  for (int d = 1; d < 16; d <<= 1)
#pragma unroll
    for (int mt = 0; mt < 4; ++mt)
#pragma unroll
      for (int rr = 0; rr < 4; ++rr) S[mt][rr] += __shfl_xor(S[mt][rr], d, 64);

  if (rl == 0) {
#pragma unroll
    for (int mt = 0; mt < 4; ++mt)
#pragma unroll
      for (int rr = 0; rr < 4; ++rr) Sp[wid][mt * 16 + hq * 4 + rr] = S[mt][rr];
  }
  __syncthreads();
  if (tid < 64) {
    const float s = Sp[0][tid] + Sp[1][tid] + Sp[2][tid] + Sp[3][tid];
    sInv[tid] = 1.0f / s;
  }
  __syncthreads();

  // scale Vt[b][c][kloc..kloc+64) by sInv — disjoint k-slices across blocks
  const int kloc = (bid >> 3) * 64;
  u16* vp = Vt + (((size_t)(batch * CC)) << 11) + kloc;
#pragma unroll 1
  for (int i = 0; i < 20; ++i) {
    const int chunk = i * 256 + tid;        // 0..5119
    const int c = chunk >> 4;               // 0..319
    const int off = (chunk & 15) * 4;       // 0..60
    u16* p = vp + (((size_t)c) << 11) + off;
    us4 v = *(const us4*)p;
    us4 o;
#pragma unroll
    for (int e2 = 0; e2 < 4; ++e2) o[e2] = f2b(b2f(v[e2]) * sInv[off + e2]);
    *(us4*)p = o;
  }
}

// ---------------------------------------------------------------------------
// K4: attention v5 — k-split 2 for occupancy.
// Block = 128 thr = 2 waves, one per k-half (wid*1024..+1024). Each wave:
// 32n x 160c, in-register softmax (mfma(Q,K) -> n=lane; exp2; cvt_pk;
// permlane32_swap), V register double-buffer issued right after E-MFMAs.
// Epilogue: wave1 -> LDS, wave0 adds + writes out.
// grid 1024 x 128 = 2048 waves = 2/SIMD, 4 blocks/CU. batch = bid&7.
// ---------------------------------------------------------------------------
__global__ __launch_bounds__(128, 2) void attn(
    const u16* __restrict__ Qb, const u16* __restrict__ Kb,
    const u16* __restrict__ Vt, const u16* __restrict__ xb,
    const float* __restrict__ gamma, float* __restrict__ out) {
  __shared__ float red[32 * 160];   // 20 KB
  const int tid = threadIdx.x;
  const int lane = tid & 63, wid = tid >> 6;
  const int r = lane & 31, h = lane >> 5;
  const int bid = blockIdx.x;
  const int b = bid & 7;
  const int rest = bid >> 3;
  const int ch = rest & 1;
  const int n0 = (rest >> 1) * 32;

  // K fragments for this n-tile (B operand of E', held all k)
  bf16x8 kf[4];
  {
    const u16* krow = Kb + (size_t)(b * NN + n0 + r) * CQ + h * 8;
#pragma unroll
    for (int qs = 0; qs < 4; ++qs) kf[qs] = *(const bf16x8*)(krow + qs * 16);
  }

  f32x16 acc[5];
#pragma unroll
  for (int j = 0; j < 5; ++j) acc[j] = zero16();

  // this wave's k-half
  const u16* qrow = Qb + (size_t)(b * NN + wid * 1024 + r) * CQ + h * 8;
  const u16* vbase = Vt + (((size_t)(b * CC + ch * 160 + r)) << 11) + wid * 1024 + h * 8;

  bf16x8 qfA[4], qfB[4];
  bf16x8 vfA[5][2], vfB[5][2];

#define LQ(QF, K0) {                                                           \
    _Pragma("unroll")                                                          \
    for (int qs = 0; qs < 4; ++qs)                                             \
      QF[qs] = *(const bf16x8*)(qrow + (size_t)(K0) * CQ + qs * 16);           \
  }
#define LV(VF, K0) {                                                           \
    _Pragma("unroll")                                                          \
    for (int j = 0; j < 5; ++j)                                                \
      _Pragma("unroll")                                                        \
      for (int ks = 0; ks < 2; ++ks)                                           \
        VF[j][ks] = *(const bf16x8*)(vbase + (((size_t)(j * 32)) << 11) +      \
                                     (K0) + ks * 16);                          \
  }
// E' -> P(bf16 A-frags) -> PV. Issues next-tile loads between E and exp.
#define TILE(QF, VF, QN, VN, KN) {                                             \
    f32x16 e = zero16();                                                       \
    _Pragma("unroll")                                                          \
    for (int qs = 0; qs < 4; ++qs)                                             \
      e = __builtin_amdgcn_mfma_f32_32x32x16_bf16(QF[qs], kf[qs], e, 0, 0, 0); \
    LQ(QN, KN)                                                                 \
    LV(VN, KN)                                                                 \
    unsigned pk0, pk1, pk2, pk3, pk4, pk5, pk6, pk7;                           \
    { float l0 = __builtin_amdgcn_exp2f(e[0]),  h0 = __builtin_amdgcn_exp2f(e[1]);  \
      float l1 = __builtin_amdgcn_exp2f(e[2]),  h1 = __builtin_amdgcn_exp2f(e[3]);  \
      float l2 = __builtin_amdgcn_exp2f(e[4]),  h2 = __builtin_amdgcn_exp2f(e[5]);  \
      float l3 = __builtin_amdgcn_exp2f(e[6]),  h3 = __builtin_amdgcn_exp2f(e[7]);  \
      float l4 = __builtin_amdgcn_exp2f(e[8]),  h4 = __builtin_amdgcn_exp2f(e[9]);  \
      float l5 = __builtin_amdgcn_exp2f(e[10]), h5 = __builtin_amdgcn_exp2f(e[11]); \
      float l6 = __builtin_amdgcn_exp2f(e[12]), h6 = __builtin_amdgcn_exp2f(e[13]); \
      float l7 = __builtin_amdgcn_exp2f(e[14]), h7 = __builtin_amdgcn_exp2f(e[15]); \
      asm("v_cvt_pk_bf16_f32 %0, %1, %2" : "=v"(pk0) : "v"(l0), "v"(h0));      \
      asm("v_cvt_pk_bf16_f32 %0, %1, %2" : "=v"(pk1) : "v"(l1), "v"(h1));      \
      asm("v_cvt_pk_bf16_f32 %0, %1, %2" : "=v"(pk2) : "v"(l2), "v"(h2));      \
      asm("v_cvt_pk_bf16_f32 %0, %1, %2" : "=v"(pk3) : "v"(l3), "v"(h3));      \
      asm("v_cvt_pk_bf16_f32 %0, %1, %2" : "=v"(pk4) : "v"(l4), "v"(h4));      \
      asm("v_cvt_pk_bf16_f32 %0, %1, %2" : "=v"(pk5) : "v"(l5), "v"(h5));      \
      asm("v_cvt_pk_bf16_f32 %0, %1, %2" : "=v"(pk6) : "v"(l6), "v"(h6));      \
      asm("v_cvt_pk_bf16_f32 %0, %1, %2" : "=v"(pk7) : "v"(l7), "v"(h7)); }    \
    asm("v_permlane32_swap_b32 %0, %1" : "+v"(pk0), "+v"(pk2));                \
    asm("v_permlane32_swap_b32 %0, %1" : "+v"(pk1), "+v"(pk3));                \
    asm("v_permlane32_swap_b32 %0, %1" : "+v"(pk4), "+v"(pk6));                \
    asm("v_permlane32_swap_b32 %0, %1" : "+v"(pk5), "+v"(pk7));                \
    u32x4 w0 = {pk0, pk1, pk2, pk3};                                           \
    u32x4 w1 = {pk4, pk5, pk6, pk7};                                           \
    bf16x8 pa0 = __builtin_bit_cast(bf16x8, w0);                               \
    bf16x8 pa1 = __builtin_bit_cast(bf16x8, w1);                               \
    _Pragma("unroll")                                                          \
    for (int j = 0; j < 5; ++j) {                                              \
      acc[j] = __builtin_amdgcn_mfma_f32_32x32x16_bf16(pa0, VF[j][0], acc[j], 0, 0, 0); \
      acc[j] = __builtin_amdgcn_mfma_f32_32x32x16_bf16(pa1, VF[j][1], acc[j], 0, 0, 0); \
    }                                                                          \
  }

  LQ(qfA, 0)
  LV(vfA, 0)
#pragma unroll 1
  for (int t = 0; t < 32; t += 2) {
    TILE(qfA, vfA, qfB, vfB, ((t + 1) & 31) * 32)
    TILE(qfB, vfB, qfA, vfA, ((t + 2) & 31) * 32)
  }
#undef TILE
#undef LQ
#undef LV

  // cross-wave reduce: wave1 -> LDS, wave0 adds and writes out
  if (wid == 1) {
#pragma unroll
    for (int reg = 0; reg < 16; ++reg) {
      const int nl = (reg & 3) + 8 * (reg >> 2) + 4 * h;
#pragma unroll
      for (int j = 0; j < 5; ++j) red[nl * 160 + j * 32 + r] = acc[j][reg];
    }
  }
  __syncthreads();
  if (wid == 0) {
    const float g = gamma[0];
#pragma unroll
    for (int reg = 0; reg < 16; ++reg) {
      const int nl = (reg & 3) + 8 * (reg >> 2) + 4 * h;
      const size_t rowb = ((size_t)(b * NN) + n0 + nl) * CC + ch * 160 + r;
#pragma unroll
      for (int j = 0; j < 5; ++j) {
        const size_t idx = rowb + (size_t)(j * 32);
        const float s = acc[j][reg] + red[nl * 160 + j * 32 + r];
        out[idx] = g * s + b2f(xb[idx]);
      }
    }
  }
}

extern "C" void kernel_launch(void* const* d_in, const int* in_sizes, int n_in,
                              void* d_out, int out_size, void* d_ws, size_t ws_size,
                              hipStream_t stream) {
  const float* x     = (const float*)d_in[0];
  const float* Wq    = (const float*)d_in[1];
  const float* bq    = (const float*)d_in[2];
  const float* Wk    = (const float*)d_in[3];
  const float* bk    = (const float*)d_in[4];
  const float* Wv    = (const float*)d_in[5];
  const float* bv    = (const float*)d_in[6];
  const float* gamma = (const float*)d_in[7];
  float* out = (float*)d_out;

  char* w = (char*)d_ws;
  u16* xb = (u16*)(w);                         // 16384*320  (10485760 B)
  u16* Wb = (u16*)(w + 10485760);              // 448*320    (286720 B)
  u16* Qb = (u16*)(w + 10772480);              // 16384*64   (2097152 B)
  u16* Kb = (u16*)(w + 12869632);              // 16384*64   (2097152 B)
  u16* Vt = (u16*)(w + 14966784);              // 8*320*2048 (10485760 B)

  cvt_x<<<5120, 256, 0, stream>>>(x, xb);
  cvt_w<<<140, 256, 0, stream>>>(Wq, Wk, Wv, Wb);
  gemm_qkv<<<dim3(7, 128), 256, 0, stream>>>(xb, Wb, bq, bk, bv, Qb, Kb, Vt);
  row_stats<<<256, 256, 0, stream>>>(Qb, Kb, Vt);
  attn<<<1024, 128, 0, stream>>>(Qb, Kb, Vt, xb, gamma, out);
}

// Round 8
// 120.981 us; speedup vs baseline: 1.5604x; 1.5604x over previous
//
#include <hip/hip_runtime.h>
#include <hip/hip_bf16.h>

#define BB 8
#define NN 2048
#define CC 320
#define CQ 64
#define LOG2E 1.4426950408889634f

typedef __attribute__((ext_vector_type(8)))  short bf16x8;
typedef __attribute__((ext_vector_type(4)))  float f32x4;
typedef __attribute__((ext_vector_type(16))) float f32x16;
typedef __attribute__((ext_vector_type(4)))  unsigned short us4;
typedef __attribute__((ext_vector_type(8)))  unsigned short us8;
typedef __attribute__((ext_vector_type(4)))  unsigned int u32x4;
typedef unsigned short u16;

// Layouts:
//  Q3[b][kt=k/32][cq8=cq/8][kl=k%32][8]  (bf16, pre-scaled by log2e)
//  Kb[b*N+n][cq]                          (row-major)
//  V3[b][kt8=k/8][c][8]                   (bf16, later scaled by 1/S[k])
// Both Q3/V3 make every MFMA fragment load lane-contiguous (8 L2 lines
// per instruction instead of 32 -> fixes the request-rate bottleneck).

static __device__ __forceinline__ u16 f2b(float f) {
  unsigned u = __builtin_bit_cast(unsigned, f);
  unsigned r = (u + 0x7FFFu + ((u >> 16) & 1u)) >> 16;
  return (u16)r;
}
static __device__ __forceinline__ float b2f(u16 s) {
  unsigned u = ((unsigned)s) << 16;
  return __builtin_bit_cast(float, u);
}

static __device__ __forceinline__ f32x16 zero16() {
  f32x16 v = {0,0,0,0, 0,0,0,0, 0,0,0,0, 0,0,0,0};
  return v;
}
static __device__ __forceinline__ f32x4 zero4() {
  f32x4 v = {0,0,0,0};
  return v;
}

// ---------------------------------------------------------------------------
// K0a: x fp32 -> xb bf16. grid 5120 x 256
// ---------------------------------------------------------------------------
__global__ __launch_bounds__(256) void cvt_x(const float* __restrict__ x,
                                             u16* __restrict__ xb) {
  const size_t i = (size_t)blockIdx.x * 256 + threadIdx.x;
  float4 v = *(const float4*)(x + i * 4);
  us4 o;
  o.x = f2b(v.x); o.y = f2b(v.y); o.z = f2b(v.z); o.w = f2b(v.w);
  *(us4*)(xb + i * 4) = o;
}

// ---------------------------------------------------------------------------
// K0b: Wq/Wk/Wv fp32 -> concat Wb[448][320] bf16. grid 140 x 256
// ---------------------------------------------------------------------------
__global__ __launch_bounds__(256) void cvt_w(const float* __restrict__ Wq,
                                             const float* __restrict__ Wk,
                                             const float* __restrict__ Wv,
                                             u16* __restrict__ Wb) {
  const int i = blockIdx.x * 256 + threadIdx.x;
  const int idx4 = i * 4;
  const int row = idx4 / CC;
  const int col = idx4 - row * CC;
  const float* src = (row < 64) ? (Wq + (size_t)row * CC)
                   : (row < 128) ? (Wk + (size_t)(row - 64) * CC)
                                 : (Wv + (size_t)(row - 128) * CC);
  float4 v = *(const float4*)(src + col);
  us4 o;
  o.x = f2b(v.x); o.y = f2b(v.y); o.z = f2b(v.z); o.w = f2b(v.w);
  *(us4*)(Wb + (size_t)row * CC + col) = o;
}

// ---------------------------------------------------------------------------
// K1: QKV GEMM. grid (7, 128). x=0: Q -> Q3 blocked (scaled by log2e),
// x=1: K -> Kb row-major, x>=2: V -> V3 blocked.
// ---------------------------------------------------------------------------
__global__ __launch_bounds__(256) void gemm_qkv(
    const u16* __restrict__ xb, const u16* __restrict__ Wb,
    const float* __restrict__ bq, const float* __restrict__ bk,
    const float* __restrict__ bv,
    u16* __restrict__ Qb, u16* __restrict__ Kb, u16* __restrict__ Vt) {
  const int tid = threadIdx.x;
  const int lane = tid & 63, wid = tid >> 6;
  const int r = lane & 31, h = lane >> 5;
  const int m0 = blockIdx.y * 128 + wid * 32;
  const int col0 = blockIdx.x * 64;

  f32x16 acc0 = zero16(), acc1 = zero16();
  const u16* xrow = xb + (size_t)(m0 + r) * CC + h * 8;
  const u16* w0 = Wb + (size_t)(col0 + r) * CC + h * 8;
  const u16* w1 = w0 + 32 * CC;

  bf16x8 a   = *(const bf16x8*)(xrow);
  bf16x8 b0v = *(const bf16x8*)(w0);
  bf16x8 b1v = *(const bf16x8*)(w1);
#pragma unroll 1
  for (int ks = 0; ks < 20; ++ks) {
    bf16x8 na, nb0, nb1;
    if (ks < 19) {
      na  = *(const bf16x8*)(xrow + (ks + 1) * 16);
      nb0 = *(const bf16x8*)(w0 + (ks + 1) * 16);
      nb1 = *(const bf16x8*)(w1 + (ks + 1) * 16);
    }
    acc0 = __builtin_amdgcn_mfma_f32_32x32x16_bf16(a, b0v, acc0, 0, 0, 0);
    acc1 = __builtin_amdgcn_mfma_f32_32x32x16_bf16(a, b1v, acc1, 0, 0, 0);
    a = na; b0v = nb0; b1v = nb1;
  }

  const int bb = m0 >> 11;        // batch
  const int mloc = m0 & 2047;     // n (or k) within batch

#pragma unroll
  for (int nt = 0; nt < 2; ++nt) {
    const int col = col0 + nt * 32 + r;
    const f32x16 A = nt ? acc1 : acc0;
    if (col0 >= 128) {
      // V3[b][kt8][c][8]: group g holds rows mloc + g*8 + 4h + {0..3}
      const int c = col - 128;
      const float bias = bv[c];
      u16* vdst = Vt + (((size_t)(bb * 256 + (mloc >> 3)) * 320 + c) * 8) + 4 * h;
#pragma unroll
      for (int g = 0; g < 4; ++g) {
        us4 o;
#pragma unroll
        for (int e = 0; e < 4; ++e) o[e] = f2b(A[g * 4 + e] + bias);
        *(us4*)(vdst + (size_t)g * 2560) = o;   // next kt8: +320*8
      }
    } else if (col0 >= 64) {
      const float bias = bk[col - 64];
#pragma unroll
      for (int reg = 0; reg < 16; ++reg) {
        const int row = m0 + (reg & 3) + 8 * (reg >> 2) + 4 * h;
        Kb[(size_t)row * CQ + (col - 64)] = f2b(A[reg] + bias);
      }
    } else {
      // Q3[b][kt][cq8][kl][8], pre-scaled by log2(e)
      const float bias = bq[col];
      const int kt = mloc >> 5;
      u16* qdst = Qb + (((size_t)(bb * 64 + kt) * 8 + (col >> 3)) * 32) * 8 + (col & 7);
#pragma unroll
      for (int reg = 0; reg < 16; ++reg) {
        const int kl = (reg & 3) + 8 * (reg >> 2) + 4 * h;
        qdst[kl * 8] = f2b((A[reg] + bias) * LOG2E);
      }
    }
  }
}

// ---------------------------------------------------------------------------
// K3: row sums + fold 1/S into V3.
// S[k] = sum_m 2^(Q'[k]·K[m]); then V3[b][k][c] *= 1/S[k] for all c.
// Block = 64 k-rows of one batch; 4 waves cover m in 512-chunks. grid 256.
// ---------------------------------------------------------------------------
__global__ __launch_bounds__(256) void row_stats(
    const u16* __restrict__ Qb, const u16* __restrict__ Kb,
    u16* __restrict__ Vt) {
  __shared__ float Sp[4][64];
  __shared__ float sInv[64];
  const int tid = threadIdx.x;
  const int lane = tid & 63, wid = tid >> 6;
  const int rl = lane & 15, hq = lane >> 4;
  const int bid = blockIdx.x;
  const int batch = bid & 7;
  const int kloc64 = (bid >> 3) * 64;

  // A-frags from Q3: rows kloc64 + mt*16 + rl, cq = qs*32 + hq*8
  bf16x8 af[4][2];
#pragma unroll
  for (int mt = 0; mt < 4; ++mt) {
    const int k_loc = kloc64 + mt * 16 + rl;
    const int kt = k_loc >> 5, kl = k_loc & 31;
#pragma unroll
    for (int qs = 0; qs < 2; ++qs)
      af[mt][qs] = *(const bf16x8*)(Qb +
          (((size_t)(batch * 64 + kt) * 8 + qs * 4 + hq) * 32 + kl) * 8);
  }

  float S[4][4];
#pragma unroll
  for (int mt = 0; mt < 4; ++mt)
#pragma unroll
    for (int rr = 0; rr < 4; ++rr) S[mt][rr] = 0.f;

  const int mstart = batch * NN + wid * 512;
  const u16* kr = Kb + (size_t)(mstart + rl) * CQ + hq * 8;
  bf16x8 c0 = *(const bf16x8*)(kr);
  bf16x8 c1 = *(const bf16x8*)(kr + 32);
#pragma unroll 1
  for (int ms = 0; ms < 32; ++ms) {
    bf16x8 n0, n1;
    if (ms < 31) {
      n0 = *(const bf16x8*)(kr + 16 * CQ);
      n1 = *(const bf16x8*)(kr + 16 * CQ + 32);
    }
#pragma unroll
    for (int mt = 0; mt < 4; ++mt) {
      f32x4 e = zero4();
      e = __builtin_amdgcn_mfma_f32_16x16x32_bf16(af[mt][0], c0, e, 0, 0, 0);
      e = __builtin_amdgcn_mfma_f32_16x16x32_bf16(af[mt][1], c1, e, 0, 0, 0);
#pragma unroll
      for (int rr = 0; rr < 4; ++rr) S[mt][rr] += __builtin_amdgcn_exp2f(e[rr]);
    }
    c0 = n0; c1 = n1; kr += 16 * CQ;
  }

#pragma unroll
  for (int d = 1; d < 16; d <<= 1)
#pragma unroll
    for (int mt = 0; mt < 4; ++mt)
#pragma unroll
      for (int rr = 0; rr < 4; ++rr) S[mt][rr] += __shfl_xor(S[mt][rr], d, 64);

  if (rl == 0) {
#pragma unroll
    for (int mt = 0; mt < 4; ++mt)
#pragma unroll
      for (int rr = 0; rr < 4; ++rr) Sp[wid][mt * 16 + hq * 4 + rr] = S[mt][rr];
  }
  __syncthreads();
  if (tid < 64) {
    const float s = Sp[0][tid] + Sp[1][tid] + Sp[2][tid] + Sp[3][tid];
    sInv[tid] = 1.0f / s;
  }
  __syncthreads();

  // scale V3[b][kt8b..kt8b+8)[c][8] by sInv — fully coalesced us4 stream
  const int kt8b = kloc64 >> 3;
#pragma unroll 1
  for (int i = 0; i < 20; ++i) {
    const int chunk = i * 256 + tid;     // 0..5119
    const int kt8l = chunk / 640;        // 0..7
    const int rem = chunk - kt8l * 640;  // 0..639
    const int c = rem >> 1;
    const int h2 = rem & 1;
    u16* p = Vt + (((size_t)(batch * 256 + kt8b + kt8l) * 320 + c) * 8) + h2 * 4;
    us4 v = *(const us4*)p;
    us4 o;
#pragma unroll
    for (int e2 = 0; e2 < 4; ++e2) o[e2] = f2b(b2f(v[e2]) * sInv[kt8l * 8 + h2 * 4 + e2]);
    *(us4*)p = o;
  }
}

// ---------------------------------------------------------------------------
// K4: attention v6 — lane-contiguous fragment loads.
// Block = 128 thr = 2 waves, one per k-half. Each wave: 32n x 160c,
// in-register softmax (mfma(Q,K) -> n=lane; exp2; cvt_pk; permlane32_swap),
// Q/V frags from blocked Q3/V3 (8 lines per load instr), V register
// double-buffer issued right after E-MFMAs. Epilogue: wave1 -> LDS,
// wave0 adds + writes out. grid 1024 x 128. batch = bid&7 (XCD-pinned).
// ---------------------------------------------------------------------------
__global__ __launch_bounds__(128, 2) void attn(
    const u16* __restrict__ Qb, const u16* __restrict__ Kb,
    const u16* __restrict__ Vt, const u16* __restrict__ xb,
    const float* __restrict__ gamma, float* __restrict__ out) {
  __shared__ float red[32 * 160];   // 20 KB
  const int tid = threadIdx.x;
  const int lane = tid & 63, wid = tid >> 6;
  const int r = lane & 31, h = lane >> 5;
  const int bid = blockIdx.x;
  const int b = bid & 7;
  const int rest = bid >> 3;
  const int ch = rest & 1;
  const int n0 = (rest >> 1) * 32;

  // K fragments for this n-tile (B operand of E', held all k) — one-time
  bf16x8 kf[4];
  {
    const u16* krow = Kb + (size_t)(b * NN + n0 + r) * CQ + h * 8;
#pragma unroll
    for (int qs = 0; qs < 4; ++qs) kf[qs] = *(const bf16x8*)(krow + qs * 16);
  }

  f32x16 acc[5];
#pragma unroll
  for (int j = 0; j < 5; ++j) acc[j] = zero16();

  // per-lane bases into blocked layouts (this wave's k-half via wid)
  // Q3 flat: b*131072 + kt*2048 + cq8*256 + kl*8   (kl=r, cq8=qs*2+h)
  const u16* qb3 = Qb + (size_t)b * 131072 + (size_t)(wid * 32) * 2048 + (size_t)r * 8;
  // V3 flat: b*655360 + kt8*2560 + c*8             (c = ch*160 + j*32 + r)
  const u16* vb3 = Vt + (size_t)b * 655360 + (size_t)(wid * 128) * 2560
                      + (size_t)(ch * 160 + r) * 8;

  bf16x8 qfA[4], qfB[4];
  bf16x8 vfA[5][2], vfB[5][2];

#define LQ(QF, K0) {                                                           \
    _Pragma("unroll")                                                          \
    for (int qs = 0; qs < 4; ++qs)                                             \
      QF[qs] = *(const bf16x8*)(qb3 + (size_t)((K0) >> 5) * 2048 +             \
                                (qs * 2 + h) * 256);                           \
  }
#define LV(VF, K0) {                                                           \
    _Pragma("unroll")                                                          \
    for (int j = 0; j < 5; ++j)                                                \
      _Pragma("unroll")                                                        \
      for (int ks = 0; ks < 2; ++ks)                                           \
        VF[j][ks] = *(const bf16x8*)(vb3 +                                     \
            (size_t)(((K0) >> 3) + ks * 2 + h) * 2560 + j * 256);              \
  }
// E' -> P(bf16 A-frags) -> PV. Issues next-tile loads between E and exp.
#define TILE(QF, VF, QN, VN, KN) {                                             \
    f32x16 e = zero16();                                                       \
    _Pragma("unroll")                                                          \
    for (int qs = 0; qs < 4; ++qs)                                             \
      e = __builtin_amdgcn_mfma_f32_32x32x16_bf16(QF[qs], kf[qs], e, 0, 0, 0); \
    LQ(QN, KN)                                                                 \
    LV(VN, KN)                                                                 \
    unsigned pk0, pk1, pk2, pk3, pk4, pk5, pk6, pk7;                           \
    { float l0 = __builtin_amdgcn_exp2f(e[0]),  h0 = __builtin_amdgcn_exp2f(e[1]);  \
      float l1 = __builtin_amdgcn_exp2f(e[2]),  h1 = __builtin_amdgcn_exp2f(e[3]);  \
      float l2 = __builtin_amdgcn_exp2f(e[4]),  h2 = __builtin_amdgcn_exp2f(e[5]);  \
      float l3 = __builtin_amdgcn_exp2f(e[6]),  h3 = __builtin_amdgcn_exp2f(e[7]);  \
      float l4 = __builtin_amdgcn_exp2f(e[8]),  h4 = __builtin_amdgcn_exp2f(e[9]);  \
      float l5 = __builtin_amdgcn_exp2f(e[10]), h5 = __builtin_amdgcn_exp2f(e[11]); \
      float l6 = __builtin_amdgcn_exp2f(e[12]), h6 = __builtin_amdgcn_exp2f(e[13]); \
      float l7 = __builtin_amdgcn_exp2f(e[14]), h7 = __builtin_amdgcn_exp2f(e[15]); \
      asm("v_cvt_pk_bf16_f32 %0, %1, %2" : "=v"(pk0) : "v"(l0), "v"(h0));      \
      asm("v_cvt_pk_bf16_f32 %0, %1, %2" : "=v"(pk1) : "v"(l1), "v"(h1));      \
      asm("v_cvt_pk_bf16_f32 %0, %1, %2" : "=v"(pk2) : "v"(l2), "v"(h2));      \
      asm("v_cvt_pk_bf16_f32 %0, %1, %2" : "=v"(pk3) : "v"(l3), "v"(h3));      \
      asm("v_cvt_pk_bf16_f32 %0, %1, %2" : "=v"(pk4) : "v"(l4), "v"(h4));      \
      asm("v_cvt_pk_bf16_f32 %0, %1, %2" : "=v"(pk5) : "v"(l5), "v"(h5));      \
      asm("v_cvt_pk_bf16_f32 %0, %1, %2" : "=v"(pk6) : "v"(l6), "v"(h6));      \
      asm("v_cvt_pk_bf16_f32 %0, %1, %2" : "=v"(pk7) : "v"(l7), "v"(h7)); }    \
    asm("v_permlane32_swap_b32 %0, %1" : "+v"(pk0), "+v"(pk2));                \
    asm("v_permlane32_swap_b32 %0, %1" : "+v"(pk1), "+v"(pk3));                \
    asm("v_permlane32_swap_b32 %0, %1" : "+v"(pk4), "+v"(pk6));                \
    asm("v_permlane32_swap_b32 %0, %1" : "+v"(pk5), "+v"(pk7));                \
    u32x4 w0 = {pk0, pk1, pk2, pk3};                                           \
    u32x4 w1 = {pk4, pk5, pk6, pk7};                                           \
    bf16x8 pa0 = __builtin_bit_cast(bf16x8, w0);                               \
    bf16x8 pa1 = __builtin_bit_cast(bf16x8, w1);                               \
    _Pragma("unroll")                                                          \
    for (int j = 0; j < 5; ++j) {                                              \
      acc[j] = __builtin_amdgcn_mfma_f32_32x32x16_bf16(pa0, VF[j][0], acc[j], 0, 0, 0); \
      acc[j] = __builtin_amdgcn_mfma_f32_32x32x16_bf16(pa1, VF[j][1], acc[j], 0, 0, 0); \
    }                                                                          \
  }

  LQ(qfA, 0)
  LV(vfA, 0)
#pragma unroll 1
  for (int t = 0; t < 32; t += 2) {
    TILE(qfA, vfA, qfB, vfB, ((t + 1) & 31) * 32)
    TILE(qfB, vfB, qfA, vfA, ((t + 2) & 31) * 32)
  }
#undef TILE
#undef LQ
#undef LV

  // cross-wave reduce: wave1 -> LDS, wave0 adds and writes out
  if (wid == 1) {
#pragma unroll
    for (int reg = 0; reg < 16; ++reg) {
      const int nl = (reg & 3) + 8 * (reg >> 2) + 4 * h;
#pragma unroll
      for (int j = 0; j < 5; ++j) red[nl * 160 + j * 32 + r] = acc[j][reg];
    }
  }
  __syncthreads();
  if (wid == 0) {
    const float g = gamma[0];
#pragma unroll
    for (int reg = 0; reg < 16; ++reg) {
      const int nl = (reg & 3) + 8 * (reg >> 2) + 4 * h;
      const size_t rowb = ((size_t)(b * NN) + n0 + nl) * CC + ch * 160 + r;
#pragma unroll
      for (int j = 0; j < 5; ++j) {
        const size_t idx = rowb + (size_t)(j * 32);
        const float s = acc[j][reg] + red[nl * 160 + j * 32 + r];
        out[idx] = g * s + b2f(xb[idx]);
      }
    }
  }
}

extern "C" void kernel_launch(void* const* d_in, const int* in_sizes, int n_in,
                              void* d_out, int out_size, void* d_ws, size_t ws_size,
                              hipStream_t stream) {
  const float* x     = (const float*)d_in[0];
  const float* Wq    = (const float*)d_in[1];
  const float* bq    = (const float*)d_in[2];
  const float* Wk    = (const float*)d_in[3];
  const float* bk    = (const float*)d_in[4];
  const float* Wv    = (const float*)d_in[5];
  const float* bv    = (const float*)d_in[6];
  const float* gamma = (const float*)d_in[7];
  float* out = (float*)d_out;

  char* w = (char*)d_ws;
  u16* xb = (u16*)(w);                         // 16384*320  (10485760 B)
  u16* Wb = (u16*)(w + 10485760);              // 448*320    (286720 B)
  u16* Qb = (u16*)(w + 10772480);              // Q3: 8*64*8*32*8 (2097152 B)
  u16* Kb = (u16*)(w + 12869632);              // 16384*64   (2097152 B)
  u16* Vt = (u16*)(w + 14966784);              // V3: 8*256*320*8 (10485760 B)

  cvt_x<<<5120, 256, 0, stream>>>(x, xb);
  cvt_w<<<140, 256, 0, stream>>>(Wq, Wk, Wv, Wb);
  gemm_qkv<<<dim3(7, 128), 256, 0, stream>>>(xb, Wb, bq, bk, bv, Qb, Kb, Vt);
  row_stats<<<256, 256, 0, stream>>>(Qb, Kb, Vt);
  attn<<<1024, 128, 0, stream>>>(Qb, Kb, Vt, xb, gamma, out);
}

// Round 10
// 114.286 us; speedup vs baseline: 1.6518x; 1.0586x over previous
//
#include <hip/hip_runtime.h>
#include <hip/hip_bf16.h>

#define BB 8
#define NN 2048
#define CC 320
#define CQ 64
#define LOG2E 1.4426950408889634f

typedef __attribute__((ext_vector_type(8)))  short bf16x8;
typedef __attribute__((ext_vector_type(4)))  float f32x4;
typedef __attribute__((ext_vector_type(16))) float f32x16;
typedef __attribute__((ext_vector_type(4)))  unsigned short us4;
typedef __attribute__((ext_vector_type(8)))  unsigned short us8;
typedef __attribute__((ext_vector_type(4)))  unsigned int u32x4;
typedef unsigned short u16;

// Layouts:
//  Q3[b][kt=k/32][cq8=cq/8][kl=k%32][8]  (bf16, pre-scaled by log2e)
//  Kb[b*N+n][cq]                          (row-major)
//  V3[b][kt8=k/8][c][8]                   (bf16, scaled by 1/S[k] in K3)

static __device__ __forceinline__ u16 f2b(float f) {
  unsigned u = __builtin_bit_cast(unsigned, f);
  unsigned r = (u + 0x7FFFu + ((u >> 16) & 1u)) >> 16;
  return (u16)r;
}
static __device__ __forceinline__ float b2f(u16 s) {
  unsigned u = ((unsigned)s) << 16;
  return __builtin_bit_cast(float, u);
}

static __device__ __forceinline__ f32x16 zero16() {
  f32x16 v = {0,0,0,0, 0,0,0,0, 0,0,0,0, 0,0,0,0};
  return v;
}
static __device__ __forceinline__ f32x4 zero4() {
  f32x4 v = {0,0,0,0};
  return v;
}

static __device__ __forceinline__ void gll16(const void* g, void* l) {
  __builtin_amdgcn_global_load_lds(
      (const __attribute__((address_space(1))) unsigned int*)g,
      (__attribute__((address_space(3))) unsigned int*)l, 16, 0, 0);
}

// ---------------------------------------------------------------------------
// K0a: x fp32 -> xb bf16. grid 5120 x 256
// ---------------------------------------------------------------------------
__global__ __launch_bounds__(256) void cvt_x(const float* __restrict__ x,
                                             u16* __restrict__ xb) {
  const size_t i = (size_t)blockIdx.x * 256 + threadIdx.x;
  float4 v = *(const float4*)(x + i * 4);
  us4 o;
  o.x = f2b(v.x); o.y = f2b(v.y); o.z = f2b(v.z); o.w = f2b(v.w);
  *(us4*)(xb + i * 4) = o;
}

// ---------------------------------------------------------------------------
// K0b: Wq/Wk/Wv fp32 -> concat Wb[448][320] bf16. grid 140 x 256
// ---------------------------------------------------------------------------
__global__ __launch_bounds__(256) void cvt_w(const float* __restrict__ Wq,
                                             const float* __restrict__ Wk,
                                             const float* __restrict__ Wv,
                                             u16* __restrict__ Wb) {
  const int i = blockIdx.x * 256 + threadIdx.x;
  const int idx4 = i * 4;
  const int row = idx4 / CC;
  const int col = idx4 - row * CC;
  const float* src = (row < 64) ? (Wq + (size_t)row * CC)
                   : (row < 128) ? (Wk + (size_t)(row - 64) * CC)
                                 : (Wv + (size_t)(row - 128) * CC);
  float4 v = *(const float4*)(src + col);
  us4 o;
  o.x = f2b(v.x); o.y = f2b(v.y); o.z = f2b(v.z); o.w = f2b(v.w);
  *(us4*)(Wb + (size_t)row * CC + col) = o;
}

// ---------------------------------------------------------------------------
// K1: QKV GEMM. grid (7, 128). x=0: Q -> Q3 blocked (scaled by log2e),
// x=1: K -> Kb row-major, x>=2: V -> V3 blocked.
// ---------------------------------------------------------------------------
__global__ __launch_bounds__(256) void gemm_qkv(
    const u16* __restrict__ xb, const u16* __restrict__ Wb,
    const float* __restrict__ bq, const float* __restrict__ bk,
    const float* __restrict__ bv,
    u16* __restrict__ Qb, u16* __restrict__ Kb, u16* __restrict__ Vt) {
  const int tid = threadIdx.x;
  const int lane = tid & 63, wid = tid >> 6;
  const int r = lane & 31, h = lane >> 5;
  const int m0 = blockIdx.y * 128 + wid * 32;
  const int col0 = blockIdx.x * 64;

  f32x16 acc0 = zero16(), acc1 = zero16();
  const u16* xrow = xb + (size_t)(m0 + r) * CC + h * 8;
  const u16* w0 = Wb + (size_t)(col0 + r) * CC + h * 8;
  const u16* w1 = w0 + 32 * CC;

  bf16x8 a   = *(const bf16x8*)(xrow);
  bf16x8 b0v = *(const bf16x8*)(w0);
  bf16x8 b1v = *(const bf16x8*)(w1);
#pragma unroll 1
  for (int ks = 0; ks < 20; ++ks) {
    bf16x8 na, nb0, nb1;
    if (ks < 19) {
      na  = *(const bf16x8*)(xrow + (ks + 1) * 16);
      nb0 = *(const bf16x8*)(w0 + (ks + 1) * 16);
      nb1 = *(const bf16x8*)(w1 + (ks + 1) * 16);
    }
    acc0 = __builtin_amdgcn_mfma_f32_32x32x16_bf16(a, b0v, acc0, 0, 0, 0);
    acc1 = __builtin_amdgcn_mfma_f32_32x32x16_bf16(a, b1v, acc1, 0, 0, 0);
    a = na; b0v = nb0; b1v = nb1;
  }

  const int bb = m0 >> 11;        // batch
  const int mloc = m0 & 2047;     // n (or k) within batch

#pragma unroll
  for (int nt = 0; nt < 2; ++nt) {
    const int col = col0 + nt * 32 + r;
    const f32x16 A = nt ? acc1 : acc0;
    if (col0 >= 128) {
      // V3[b][kt8][c][8]: group g holds rows mloc + g*8 + 4h + {0..3}
      const int c = col - 128;
      const float bias = bv[c];
      u16* vdst = Vt + (((size_t)(bb * 256 + (mloc >> 3)) * 320 + c) * 8) + 4 * h;
#pragma unroll
      for (int g = 0; g < 4; ++g) {
        us4 o;
#pragma unroll
        for (int e = 0; e < 4; ++e) o[e] = f2b(A[g * 4 + e] + bias);
        *(us4*)(vdst + (size_t)g * 2560) = o;   // next kt8: +320*8
      }
    } else if (col0 >= 64) {
      const float bias = bk[col - 64];
#pragma unroll
      for (int reg = 0; reg < 16; ++reg) {
        const int row = m0 + (reg & 3) + 8 * (reg >> 2) + 4 * h;
        Kb[(size_t)row * CQ + (col - 64)] = f2b(A[reg] + bias);
      }
    } else {
      // Q3[b][kt][cq8][kl][8], pre-scaled by log2(e)
      const float bias = bq[col];
      const int kt = mloc >> 5;
      u16* qdst = Qb + (((size_t)(bb * 64 + kt) * 8 + (col >> 3)) * 32) * 8 + (col & 7);
#pragma unroll
      for (int reg = 0; reg < 16; ++reg) {
        const int kl = (reg & 3) + 8 * (reg >> 2) + 4 * h;
        qdst[kl * 8] = f2b((A[reg] + bias) * LOG2E);
      }
    }
  }
}

// ---------------------------------------------------------------------------
// K3: row sums + fold 1/S into V3. 8 waves (512 thr), grid 256 (8b x 32 kblk).
// S[k] = sum_m 2^(Q'[k]·K[m]); then V3[b][k][c] *= 1/S[k] for all c.
// ---------------------------------------------------------------------------
__global__ __launch_bounds__(512) void row_stats(
    const u16* __restrict__ Qb, const u16* __restrict__ Kb,
    u16* __restrict__ Vt) {
  __shared__ float Sp[8][64];
  __shared__ float sInv[64];
  const int tid = threadIdx.x;
  const int lane = tid & 63, wid = tid >> 6;   // 0..7
  const int rl = lane & 15, hq = lane >> 4;
  const int bid = blockIdx.x;
  const int batch = bid & 7;
  const int kloc64 = (bid >> 3) * 64;          // bid>>3 in [0,32)

  // A-frags from Q3: rows kloc64 + mt*16 + rl, cq = qs*32 + hq*8
  bf16x8 af[4][2];
#pragma unroll
  for (int mt = 0; mt < 4; ++mt) {
    const int k_loc = kloc64 + mt * 16 + rl;
    const int kt = k_loc >> 5, kl = k_loc & 31;
#pragma unroll
    for (int qs = 0; qs < 2; ++qs)
      af[mt][qs] = *(const bf16x8*)(Qb +
          (((size_t)(batch * 64 + kt) * 8 + qs * 4 + hq) * 32 + kl) * 8);
  }

  float S[4][4];
#pragma unroll
  for (int mt = 0; mt < 4; ++mt)
#pragma unroll
    for (int rr = 0; rr < 4; ++rr) S[mt][rr] = 0.f;

  const int mstart = batch * NN + wid * 256;
  const u16* kr = Kb + (size_t)(mstart + rl) * CQ + hq * 8;
  bf16x8 c0 = *(const bf16x8*)(kr);
  bf16x8 c1 = *(const bf16x8*)(kr + 32);
#pragma unroll 1
  for (int ms = 0; ms < 16; ++ms) {
    bf16x8 n0, n1;
    if (ms < 15) {
      n0 = *(const bf16x8*)(kr + 16 * CQ);
      n1 = *(const bf16x8*)(kr + 16 * CQ + 32);
    }
#pragma unroll
    for (int mt = 0; mt < 4; ++mt) {
      f32x4 e = zero4();
      e = __builtin_amdgcn_mfma_f32_16x16x32_bf16(af[mt][0], c0, e, 0, 0, 0);
      e = __builtin_amdgcn_mfma_f32_16x16x32_bf16(af[mt][1], c1, e, 0, 0, 0);
#pragma unroll
      for (int rr = 0; rr < 4; ++rr) S[mt][rr] += __builtin_amdgcn_exp2f(e[rr]);
    }
    c0 = n0; c1 = n1; kr += 16 * CQ;
  }

#pragma unroll
  for (int d = 1; d < 16; d <<= 1)
#pragma unroll
    for (int mt = 0; mt < 4; ++mt)
#pragma unroll
      for (int rr = 0; rr < 4; ++rr) S[mt][rr] += __shfl_xor(S[mt][rr], d, 64);

  if (rl == 0) {
#pragma unroll
    for (int mt = 0; mt < 4; ++mt)
#pragma unroll
      for (int rr = 0; rr < 4; ++rr) Sp[wid][mt * 16 + hq * 4 + rr] = S[mt][rr];
  }
  __syncthreads();
  if (tid < 64) {
    float s = 0.f;
#pragma unroll
    for (int p = 0; p < 8; ++p) s += Sp[p][tid];
    sInv[tid] = 1.0f / s;
  }
  __syncthreads();

  // scale V3[b][kt8b..kt8b+8)[c][8] by sInv — fully coalesced us4 stream
  const int kt8b = kloc64 >> 3;
#pragma unroll 1
  for (int i = 0; i < 10; ++i) {
    const int chunk = i * 512 + tid;     // 0..5119
    const int kt8l = chunk / 640;        // 0..7
    const int rem = chunk - kt8l * 640;  // 0..639
    const int c = rem >> 1;
    const int h2 = rem & 1;
    u16* p = Vt + (((size_t)(batch * 256 + kt8b + kt8l) * 320 + c) * 8) + h2 * 4;
    us4 v = *(const us4*)p;
    us4 o;
#pragma unroll
    for (int e2 = 0; e2 < 4; ++e2) o[e2] = f2b(b2f(v[e2]) * sInv[kt8l * 8 + h2 * 4 + e2]);
    *(us4*)p = o;
  }
}

// ---------------------------------------------------------------------------
// K4: attention v7 — LDS-staged, paired waves.
// Block = 256 thr = 4 waves: (wn = n-tile 0/1) x (kh = k-half 0/1).
// Grid 512 = 8b x 2ch x 32 n-pairs. Per k-tile (32k) the block stages ONCE
// via global_load_lds: Q(4KB) + V(10KB) per kh = 28KB, double-buffered
// (57KB LDS, 2 blocks/CU, 8 waves/CU). Both wn-waves consume the same
// chunks -> L2 traffic halved; staging leads compute by a full tile.
// ---------------------------------------------------------------------------
__global__ __launch_bounds__(256, 2) void attn(
    const u16* __restrict__ Qb, const u16* __restrict__ Kb,
    const u16* __restrict__ Vt, const u16* __restrict__ xb,
    const float* __restrict__ gamma, float* __restrict__ out) {
  __shared__ __align__(16) char LDSRAW[57344];   // 2 bufs x 2 kh x 14336
  const int tid = threadIdx.x;
  const int lane = tid & 63, wid = tid >> 6;
  const int wn = wid >> 1;       // n-tile within pair
  const int kh = wid & 1;        // k-half
  const int r = lane & 31, h = lane >> 5;
  const int bid = blockIdx.x;
  const int b = bid & 7;
  const int rest = bid >> 3;
  const int ch = rest & 1;
  const int n0 = (rest >> 1) * 64;

  // K fragments for n-tile n0 + wn*32 (held all k)
  bf16x8 kf[4];
  {
    const u16* krow = Kb + (size_t)(b * NN + n0 + wn * 32 + r) * CQ + h * 8;
#pragma unroll
    for (int qs = 0; qs < 4; ++qs) kf[qs] = *(const bf16x8*)(krow + qs * 16);
  }

  f32x16 acc[5];
#pragma unroll
  for (int j = 0; j < 5; ++j) acc[j] = zero16();

  // stage: 28 chunks of 1KB (4 Q + 10 V per kh), wave w takes [w*7, w*7+7)
#define STAGE(TN, BUF) {                                                       \
    _Pragma("unroll")                                                          \
    for (int i_ = 0; i_ < 7; ++i_) {                                           \
      const int c_ = wid * 7 + i_;                                             \
      const int khc_ = c_ / 14;                                                \
      const int rem_ = c_ % 14;                                                \
      char* dst_ = LDSRAW + (BUF) * 28672 + khc_ * 14336 + rem_ * 1024;        \
      if (rem_ < 4) {                                                          \
        const u16* src_ = Qb + ((size_t)(b * 64 + khc_ * 32 + (TN)) * 2048)    \
                             + rem_ * 512 + lane * 8;                          \
        gll16(src_, dst_);                                                     \
      } else {                                                                 \
        const int v_ = rem_ - 4;                                               \
        const int off_ = v_ * 512 + lane * 8;                                  \
        const int row_ = off_ / 1280;                                          \
        const int win_ = off_ - row_ * 1280;                                   \
        const u16* src_ = Vt +                                                 \
            ((size_t)(b * 256 + khc_ * 128 + (TN) * 4 + row_) * 320            \
             + ch * 160) * 8 + win_;                                           \
        gll16(src_, dst_);                                                     \
      }                                                                        \
    }                                                                          \
  }

#define COMPUTE(T) {                                                           \
    const char* base_ = LDSRAW + ((T) & 1) * 28672 + kh * 14336;               \
    bf16x8 qf[4];                                                              \
    _Pragma("unroll")                                                          \
    for (int qs = 0; qs < 4; ++qs)                                             \
      qf[qs] = *(const bf16x8*)(base_ + (qs * 2 + h) * 512 + r * 16);          \
    f32x16 e = zero16();                                                       \
    _Pragma("unroll")                                                          \
    for (int qs = 0; qs < 4; ++qs)                                             \
      e = __builtin_amdgcn_mfma_f32_32x32x16_bf16(qf[qs], kf[qs], e, 0, 0, 0); \
    bf16x8 vf[5][2];                                                           \
    _Pragma("unroll")                                                          \
    for (int j = 0; j < 5; ++j)                                                \
      _Pragma("unroll")                                                        \
      for (int ks = 0; ks < 2; ++ks)                                           \
        vf[j][ks] = *(const bf16x8*)(base_ + 4096 + (ks * 2 + h) * 2560        \
                                     + (j * 32 + r) * 16);                     \
    unsigned pk0, pk1, pk2, pk3, pk4, pk5, pk6, pk7;                           \
    { float l0 = __builtin_amdgcn_exp2f(e[0]),  h0 = __builtin_amdgcn_exp2f(e[1]);  \
      float l1 = __builtin_amdgcn_exp2f(e[2]),  h1 = __builtin_amdgcn_exp2f(e[3]);  \
      float l2 = __builtin_amdgcn_exp2f(e[4]),  h2 = __builtin_amdgcn_exp2f(e[5]);  \
      float l3 = __builtin_amdgcn_exp2f(e[6]),  h3 = __builtin_amdgcn_exp2f(e[7]);  \
      float l4 = __builtin_amdgcn_exp2f(e[8]),  h4 = __builtin_amdgcn_exp2f(e[9]);  \
      float l5 = __builtin_amdgcn_exp2f(e[10]), h5 = __builtin_amdgcn_exp2f(e[11]); \
      float l6 = __builtin_amdgcn_exp2f(e[12]), h6 = __builtin_amdgcn_exp2f(e[13]); \
      float l7 = __builtin_amdgcn_exp2f(e[14]), h7 = __builtin_amdgcn_exp2f(e[15]); \
      asm("v_cvt_pk_bf16_f32 %0, %1, %2" : "=v"(pk0) : "v"(l0), "v"(h0));      \
      asm("v_cvt_pk_bf16_f32 %0, %1, %2" : "=v"(pk1) : "v"(l1), "v"(h1));      \
      asm("v_cvt_pk_bf16_f32 %0, %1, %2" : "=v"(pk2) : "v"(l2), "v"(h2));      \
      asm("v_cvt_pk_bf16_f32 %0, %1, %2" : "=v"(pk3) : "v"(l3), "v"(h3));      \
      asm("v_cvt_pk_bf16_f32 %0, %1, %2" : "=v"(pk4) : "v"(l4), "v"(h4));      \
      asm("v_cvt_pk_bf16_f32 %0, %1, %2" : "=v"(pk5) : "v"(l5), "v"(h5));      \
      asm("v_cvt_pk_bf16_f32 %0, %1, %2" : "=v"(pk6) : "v"(l6), "v"(h6));      \
      asm("v_cvt_pk_bf16_f32 %0, %1, %2" : "=v"(pk7) : "v"(l7), "v"(h7)); }    \
    asm("v_permlane32_swap_b32 %0, %1" : "+v"(pk0), "+v"(pk2));                \
    asm("v_permlane32_swap_b32 %0, %1" : "+v"(pk1), "+v"(pk3));                \
    asm("v_permlane32_swap_b32 %0, %1" : "+v"(pk4), "+v"(pk6));                \
    asm("v_permlane32_swap_b32 %0, %1" : "+v"(pk5), "+v"(pk7));                \
    u32x4 w0_ = {pk0, pk1, pk2, pk3};                                          \
    u32x4 w1_ = {pk4, pk5, pk6, pk7};                                          \
    bf16x8 pa0 = __builtin_bit_cast(bf16x8, w0_);                              \
    bf16x8 pa1 = __builtin_bit_cast(bf16x8, w1_);                              \
    _Pragma("unroll")                                                          \
    for (int j = 0; j < 5; ++j) {                                              \
      acc[j] = __builtin_amdgcn_mfma_f32_32x32x16_bf16(pa0, vf[j][0], acc[j], 0, 0, 0); \
      acc[j] = __builtin_amdgcn_mfma_f32_32x32x16_bf16(pa1, vf[j][1], acc[j], 0, 0, 0); \
    }                                                                          \
  }

  STAGE(0, 0);
  __syncthreads();
#pragma unroll 1
  for (int t = 0; t < 32; ++t) {
    if (t < 31) STAGE(t + 1, (t + 1) & 1);
    COMPUTE(t);
    __syncthreads();
  }
#undef STAGE
#undef COMPUTE

  // kh=1 waves dump partial sums; kh=0 waves combine and write out
  float* red = (float*)LDSRAW;   // 2 regions x 5120 f32 = 40 KB
  if (kh == 1) {
#pragma unroll
    for (int reg = 0; reg < 16; ++reg) {
      const int nl = (reg & 3) + 8 * (reg >> 2) + 4 * h;
#pragma unroll
      for (int j = 0; j < 5; ++j)
        red[wn * 5120 + nl * 160 + j * 32 + r] = acc[j][reg];
    }
  }
  __syncthreads();
  if (kh == 0) {
    const float g = gamma[0];
#pragma unroll
    for (int reg = 0; reg < 16; ++reg) {
      const int nl = (reg & 3) + 8 * (reg >> 2) + 4 * h;
      const size_t rowb = ((size_t)(b * NN) + n0 + wn * 32 + nl) * CC + ch * 160 + r;
#pragma unroll
      for (int j = 0; j < 5; ++j) {
        const size_t idx = rowb + (size_t)(j * 32);
        const float s = acc[j][reg] + red[wn * 5120 + nl * 160 + j * 32 + r];
        out[idx] = g * s + b2f(xb[idx]);
      }
    }
  }
}

extern "C" void kernel_launch(void* const* d_in, const int* in_sizes, int n_in,
                              void* d_out, int out_size, void* d_ws, size_t ws_size,
                              hipStream_t stream) {
  const float* x     = (const float*)d_in[0];
  const float* Wq    = (const float*)d_in[1];
  const float* bq    = (const float*)d_in[2];
  const float* Wk    = (const float*)d_in[3];
  const float* bk    = (const float*)d_in[4];
  const float* Wv    = (const float*)d_in[5];
  const float* bv    = (const float*)d_in[6];
  const float* gamma = (const float*)d_in[7];
  float* out = (float*)d_out;

  char* w = (char*)d_ws;
  u16* xb = (u16*)(w);                         // 16384*320  (10485760 B)
  u16* Wb = (u16*)(w + 10485760);              // 448*320    (286720 B)
  u16* Qb = (u16*)(w + 10772480);              // Q3: 8*64*8*32*8 (2097152 B)
  u16* Kb = (u16*)(w + 12869632);              // 16384*64   (2097152 B)
  u16* Vt = (u16*)(w + 14966784);              // V3: 8*256*320*8 (10485760 B)

  cvt_x<<<5120, 256, 0, stream>>>(x, xb);
  cvt_w<<<140, 256, 0, stream>>>(Wq, Wk, Wv, Wb);
  gemm_qkv<<<dim3(7, 128), 256, 0, stream>>>(xb, Wb, bq, bk, bv, Qb, Kb, Vt);
  row_stats<<<256, 512, 0, stream>>>(Qb, Kb, Vt);   // grid 256 (was 512: OOB bug)
  attn<<<512, 256, 0, stream>>>(Qb, Kb, Vt, xb, gamma, out);
}